// Round 1
// baseline (2318.209 us; speedup 1.0000x reference)
//
#include <hip/hip_runtime.h>
#include <cstdint>
#include <cstddef>

#define T_LEN   4096
#define B_SZ    32
#define H_DIM   128
#define DX      128
#define K_CLS   10
#define CHUNK   32
#define NCHUNKS (T_LEN / CHUNK)
#define XA_LD   136   // f16, +8 pad keeps 16B align & breaks bank conflicts
#define XH_LD   392   // f16
#define HIST_LD 136   // f16

typedef _Float16 half2v  __attribute__((ext_vector_type(2)));
typedef _Float16 half8   __attribute__((ext_vector_type(8)));
typedef float    floatx4 __attribute__((ext_vector_type(4)));

__device__ __forceinline__ float dot2f(unsigned int w, unsigned int h, float acc) {
  return __builtin_amdgcn_fdot2(__builtin_bit_cast(half2v, w),
                                __builtin_bit_cast(half2v, h), acc, false);
}

__device__ __forceinline__ unsigned int packh2(float a, float b) {
  half2v h;
  h.x = (_Float16)a;
  h.y = (_Float16)b;
  return __builtin_bit_cast(unsigned int, h);
}

__device__ __forceinline__ float sigm(float x) {
  x = fminf(fmaxf(x, -30.f), 30.f);
  return __builtin_amdgcn_rcpf(1.f + __expf(-x));
}

__device__ __forceinline__ float tanhfast(float x) {
  x = fminf(fmaxf(x, -15.f), 15.f);
  float t = __expf(-2.f * x);
  return (1.f - t) * __builtin_amdgcn_rcpf(1.f + t);
}

// out[b,t,k] = b_fc[k]  (atomicAdd accumulates both direction contributions later)
__global__ void __launch_bounds__(256) init_out_kernel(float* __restrict__ out,
                                                       const float* __restrict__ bfc) {
  int i = blockIdx.x * 256 + threadIdx.x;
  if (i < B_SZ * T_LEN * K_CLS) out[i] = bfc[i % K_CLS];
}

__global__ void __launch_bounds__(512, 2)
gru_bidir_kernel(const float* __restrict__ x,
                 const float* __restrict__ Wih_f, const float* __restrict__ Whh_f,
                 const float* __restrict__ bih_f, const float* __restrict__ bhh_f,
                 const float* __restrict__ Wih_b, const float* __restrict__ Whh_b,
                 const float* __restrict__ bih_b, const float* __restrict__ bhh_b,
                 const float* __restrict__ Wfc, float* __restrict__ out) {
  const int tid  = threadIdx.x;
  const int bid  = blockIdx.x;
  const int b    = bid & (B_SZ - 1);
  const int dir  = bid >> 5;           // 0 fwd, 1 bwd

  const float* Wih = dir ? Wih_b : Wih_f;
  const float* Whh = dir ? Whh_b : Whh_f;
  const float* bih = dir ? bih_b : bih_f;
  const float* bhh = dir ? bhh_b : bhh_f;

  const int lane = tid & 63;
  const int wv   = tid >> 6;           // wave 0..7
  const int col  = lane & 15;          // MFMA row-in-tile / col-in-tile index
  const int quad = lane >> 4;          // MFMA k-group
  const int j    = tid >> 2;           // hidden row 0..127 (scan)
  const int q    = tid & 3;            // k-quarter 0..3 (scan)

  __shared__ __align__(16) _Float16 xA[CHUNK][XA_LD];     // x chunk, f16
  __shared__ _Float16 xh[CHUNK][XH_LD];                   // xp chunk (no bias), f16
  __shared__ __align__(16) _Float16 hist[CHUNK][HIST_LD]; // h history for FC
  __shared__ __align__(16) _Float16 hbuf[2][128];         // double-buffered h

  // ---- preload recurrent weights as packed f16 pairs (registers) ----
  unsigned int whr[16], whz[16], whn[16];
  {
    const float* Wr = Whh + (size_t)j * H_DIM + q * 32;
    const float* Wz = Whh + (size_t)(H_DIM + j) * H_DIM + q * 32;
    const float* Wn = Whh + (size_t)(2 * H_DIM + j) * H_DIM + q * 32;
#pragma unroll
    for (int i = 0; i < 16; ++i) {
      whr[i] = packh2(Wr[2 * i], Wr[2 * i + 1]);
      whz[i] = packh2(Wz[2 * i], Wz[2 * i + 1]);
      whn[i] = packh2(Wn[2 * i], Wn[2 * i + 1]);
    }
  }
  const float bhr = bhh[j], bhz = bhh[H_DIM + j], bhn = bhh[2 * H_DIM + j];
  const float bir = bih[j], biz = bih[H_DIM + j], bin_ = bih[2 * H_DIM + j];

  // ---- preload Wih MFMA B-fragments: B[k][g] = Wih[g][k] ----
  // wave wv handles gate-tiles {3wv, 3wv+1, 3wv+2}; lane holds B[ks*32+quad*8+e][g0+col]
  half8 bfrag[3][4];
#pragma unroll
  for (int nt = 0; nt < 3; ++nt) {
    int g = (wv * 3 + nt) * 16 + col;
#pragma unroll
    for (int ks = 0; ks < 4; ++ks) {
      const float* src = Wih + (size_t)g * DX + ks * 32 + quad * 8;
      half8 v;
#pragma unroll
      for (int e = 0; e < 8; ++e) v[e] = (_Float16)src[e];
      bfrag[nt][ks] = v;
    }
  }

  // ---- preload Wfc fragments: B[c][k_cls] = Wfc[k_cls][dir*128 + c] ----
  half8 fcfrag[4];
#pragma unroll
  for (int ks = 0; ks < 4; ++ks) {
    half8 v;
#pragma unroll
    for (int e = 0; e < 8; ++e) {
      int c = ks * 32 + quad * 8 + e;
      v[e] = (col < K_CLS) ? (_Float16)Wfc[(size_t)col * (2 * H_DIM) + dir * H_DIM + c]
                           : (_Float16)0.f;
    }
    fcfrag[ks] = v;
  }

  // ---- init h = 0 ----
  if (tid < 128) hbuf[0][tid] = (_Float16)0.f;

  // ---- prefetch x chunk 0 into registers ----
  const int s_row = tid >> 4;   // 0..31 (timestep within chunk)
  const int dgrp  = tid & 15;   // 8-float group within Dx
  float4 px0, px1;
  {
    int t0 = dir ? (T_LEN - 1 - s_row) : s_row;
    const float* xp = x + ((size_t)b * T_LEN + t0) * DX + dgrp * 8;
    px0 = *(const float4*)xp;
    px1 = *(const float4*)(xp + 4);
  }

  float hold = 0.f;   // owner's h[j]
  __syncthreads();

  for (int c = 0; c < NCHUNKS; ++c) {
    // stage prefetched x chunk into LDS (f16)
    {
      half8 v;
      v[0] = (_Float16)px0.x; v[1] = (_Float16)px0.y;
      v[2] = (_Float16)px0.z; v[3] = (_Float16)px0.w;
      v[4] = (_Float16)px1.x; v[5] = (_Float16)px1.y;
      v[6] = (_Float16)px1.z; v[7] = (_Float16)px1.w;
      *(half8*)&xA[s_row][dgrp * 8] = v;
    }
    __syncthreads();

    // ---- MFMA: xp[s][g] = sum_d x[s][d] * Wih[g][d] for this chunk ----
    {
      floatx4 acc[2][3];
#pragma unroll
      for (int mt = 0; mt < 2; ++mt)
#pragma unroll
        for (int nt = 0; nt < 3; ++nt) acc[mt][nt] = (floatx4){0.f, 0.f, 0.f, 0.f};

#pragma unroll
      for (int mt = 0; mt < 2; ++mt) {
#pragma unroll
        for (int ks = 0; ks < 4; ++ks) {
          half8 af = *(const half8*)&xA[mt * 16 + col][ks * 32 + quad * 8];
          acc[mt][0] = __builtin_amdgcn_mfma_f32_16x16x32_f16(af, bfrag[0][ks], acc[mt][0], 0, 0, 0);
          acc[mt][1] = __builtin_amdgcn_mfma_f32_16x16x32_f16(af, bfrag[1][ks], acc[mt][1], 0, 0, 0);
          acc[mt][2] = __builtin_amdgcn_mfma_f32_16x16x32_f16(af, bfrag[2][ks], acc[mt][2], 0, 0, 0);
        }
      }

      // prefetch next chunk's x while MFMA results settle
      if (c + 1 < NCHUNKS) {
        int s = (c + 1) * CHUNK + s_row;
        int t0 = dir ? (T_LEN - 1 - s) : s;
        const float* xp = x + ((size_t)b * T_LEN + t0) * DX + dgrp * 8;
        px0 = *(const float4*)xp;
        px1 = *(const float4*)(xp + 4);
      }

      // D layout: row = quad*4+i (time), col = lane&15 (gate)
#pragma unroll
      for (int mt = 0; mt < 2; ++mt)
#pragma unroll
        for (int nt = 0; nt < 3; ++nt)
#pragma unroll
          for (int i = 0; i < 4; ++i)
            xh[mt * 16 + quad * 4 + i][(wv * 3 + nt) * 16 + col] = (_Float16)acc[mt][nt][i];
    }
    __syncthreads();

    // ---- sequential scan over the chunk ----
    int p = 0;
    for (int s = 0; s < CHUNK; ++s) {
      const uint4* hb = (const uint4*)&hbuf[p][0];
      uint4 h0 = hb[q * 4 + 0];
      uint4 h1 = hb[q * 4 + 1];
      uint4 h2 = hb[q * 4 + 2];
      uint4 h3 = hb[q * 4 + 3];
      unsigned int hh[16];
      hh[0] = h0.x;  hh[1] = h0.y;  hh[2] = h0.z;  hh[3] = h0.w;
      hh[4] = h1.x;  hh[5] = h1.y;  hh[6] = h1.z;  hh[7] = h1.w;
      hh[8] = h2.x;  hh[9] = h2.y;  hh[10] = h2.z; hh[11] = h2.w;
      hh[12] = h3.x; hh[13] = h3.y; hh[14] = h3.z; hh[15] = h3.w;

      float ar0 = 0.f, ar1 = 0.f, az0 = 0.f, az1 = 0.f, an0 = 0.f, an1 = 0.f;
#pragma unroll
      for (int i = 0; i < 8; ++i) {
        ar0 = dot2f(whr[2 * i],     hh[2 * i],     ar0);
        ar1 = dot2f(whr[2 * i + 1], hh[2 * i + 1], ar1);
        az0 = dot2f(whz[2 * i],     hh[2 * i],     az0);
        az1 = dot2f(whz[2 * i + 1], hh[2 * i + 1], az1);
        an0 = dot2f(whn[2 * i],     hh[2 * i],     an0);
        an1 = dot2f(whn[2 * i + 1], hh[2 * i + 1], an1);
      }
      float ar = ar0 + ar1, az = az0 + az1, an = an0 + an1;
      ar += __shfl_xor(ar, 1); ar += __shfl_xor(ar, 2);
      az += __shfl_xor(az, 1); az += __shfl_xor(az, 2);
      an += __shfl_xor(an, 1); an += __shfl_xor(an, 2);

      if (q == 0) {
        float rr = sigm(((float)xh[s][j] + bir) + (ar + bhr));
        float zz = sigm(((float)xh[s][H_DIM + j] + biz) + (az + bhz));
        float nn = tanhfast(((float)xh[s][2 * H_DIM + j] + bin_) + rr * (an + bhn));
        hold = (1.f - zz) * nn + zz * hold;
        _Float16 hf = (_Float16)hold;
        hbuf[p ^ 1][j] = hf;
        hist[s][j] = hf;
      }
      p ^= 1;
      __syncthreads();
    }

    // ---- fused FC for this chunk: out[t][k] += hist[t][:] . Wfc[k][dir*128:] ----
    if (wv < 2) {
      floatx4 facc = (floatx4){0.f, 0.f, 0.f, 0.f};
      int mt = wv;
#pragma unroll
      for (int ks = 0; ks < 4; ++ks) {
        half8 af = *(const half8*)&hist[mt * 16 + col][ks * 32 + quad * 8];
        facc = __builtin_amdgcn_mfma_f32_16x16x32_f16(af, fcfrag[ks], facc, 0, 0, 0);
      }
      if (col < K_CLS) {
#pragma unroll
        for (int i = 0; i < 4; ++i) {
          int s = mt * 16 + quad * 4 + i;
          int t = c * CHUNK + s;
          int tt = dir ? (T_LEN - 1 - t) : t;
          atomicAdd(out + ((size_t)b * T_LEN + tt) * K_CLS + col, facc[i]);
        }
      }
    }
    // next iteration's xA store is fenced from this chunk's reads by the scan barriers
  }
}

extern "C" void kernel_launch(void* const* d_in, const int* in_sizes, int n_in,
                              void* d_out, int out_size, void* d_ws, size_t ws_size,
                              hipStream_t stream) {
  (void)in_sizes; (void)n_in; (void)d_ws; (void)ws_size; (void)out_size;
  const float* x     = (const float*)d_in[0];
  const float* Wih_f = (const float*)d_in[1];
  const float* Whh_f = (const float*)d_in[2];
  const float* bih_f = (const float*)d_in[3];
  const float* bhh_f = (const float*)d_in[4];
  const float* Wih_b = (const float*)d_in[5];
  const float* Whh_b = (const float*)d_in[6];
  const float* bih_b = (const float*)d_in[7];
  const float* bhh_b = (const float*)d_in[8];
  const float* Wfc   = (const float*)d_in[9];
  const float* bfc   = (const float*)d_in[10];
  float* out = (float*)d_out;

  const int n_out = B_SZ * T_LEN * K_CLS;
  init_out_kernel<<<(n_out + 255) / 256, 256, 0, stream>>>(out, bfc);
  gru_bidir_kernel<<<B_SZ * 2, 512, 0, stream>>>(x, Wih_f, Whh_f, bih_f, bhh_f,
                                                 Wih_b, Whh_b, bih_b, bhh_b, Wfc, out);
}

// Round 2
// 2007.750 us; speedup vs baseline: 1.1546x; 1.1546x over previous
//
#include <hip/hip_runtime.h>
#include <cstdint>
#include <cstddef>

#define T_LEN   4096
#define B_SZ    32
#define H_DIM   128
#define DX      128
#define K_CLS   10
#define CHUNK   32
#define NCHUNKS (T_LEN / CHUNK)
#define XA_LD   136   // f16 halves per xA row
#define HIST_LD 136

typedef _Float16 half2v  __attribute__((ext_vector_type(2)));
typedef _Float16 half8   __attribute__((ext_vector_type(8)));
typedef float    floatx4 __attribute__((ext_vector_type(4)));

__device__ __forceinline__ float dot2f(unsigned int w, unsigned int h, float acc) {
  return __builtin_amdgcn_fdot2(__builtin_bit_cast(half2v, w),
                                __builtin_bit_cast(half2v, h), acc, false);
}

__device__ __forceinline__ unsigned int packh2(float a, float b) {
  half2v h;
  h.x = (_Float16)a;
  h.y = (_Float16)b;
  return __builtin_bit_cast(unsigned int, h);
}

// x + x(lane^1) via DPP quad_perm(1,0,3,2) — both lanes of the pair get the sum.
__device__ __forceinline__ float dpp_xor1_add(float x) {
  int xi = __builtin_bit_cast(int, x);
  int yi = __builtin_amdgcn_update_dpp(xi, xi, 0xB1, 0xF, 0xF, false);
  return x + __builtin_bit_cast(float, yi);
}

__device__ __forceinline__ float sigm(float x) {
  x = fminf(fmaxf(x, -30.f), 30.f);
  return __builtin_amdgcn_rcpf(1.f + __expf(-x));
}

__device__ __forceinline__ float tanhfast(float x) {
  x = fminf(fmaxf(x, -15.f), 15.f);
  float t = __expf(-2.f * x);
  return (1.f - t) * __builtin_amdgcn_rcpf(1.f + t);
}

__global__ void __launch_bounds__(256) init_out_kernel(float* __restrict__ out,
                                                       const float* __restrict__ bfc) {
  int i = blockIdx.x * 256 + threadIdx.x;
  if (i < B_SZ * T_LEN * K_CLS) out[i] = bfc[i % K_CLS];
}

__global__ void __launch_bounds__(256, 1)
gru_bidir_kernel(const float* __restrict__ x,
                 const float* __restrict__ Wih_f, const float* __restrict__ Whh_f,
                 const float* __restrict__ bih_f, const float* __restrict__ bhh_f,
                 const float* __restrict__ Wih_b, const float* __restrict__ Whh_b,
                 const float* __restrict__ bih_b, const float* __restrict__ bhh_b,
                 const float* __restrict__ Wfc, float* __restrict__ out) {
  const int tid = threadIdx.x;
  const int bid = blockIdx.x;
  const int b   = bid & (B_SZ - 1);
  const int dir = bid >> 5;

  const float* Wih = dir ? Wih_b : Wih_f;
  const float* Whh = dir ? Whh_b : Whh_f;
  const float* bih = dir ? bih_b : bih_f;
  const float* bhh = dir ? bhh_b : bhh_f;

  const int lane = tid & 63;
  const int wv   = tid >> 6;   // 0..3
  const int col  = lane & 15;
  const int quad = lane >> 4;
  const int j    = tid >> 1;   // 0..127 hidden row (scan)
  const int q    = tid & 1;    // k-half (scan)

  __shared__ __align__(16) _Float16 xA[CHUNK][XA_LD];
  __shared__ __align__(16) _Float16 xh2[CHUNK][4 * H_DIM];  // [s][j*4 + gate]
  __shared__ __align__(16) _Float16 hist[CHUNK][HIST_LD];
  __shared__ __align__(16) _Float16 hbuf[2][H_DIM];

  // ---- recurrent weights: 32 packed f16 pairs per gate (this thread's k-half) ----
  unsigned int whr[32], whz[32], whn[32];
  {
    const float* Wr = Whh + (size_t)j * H_DIM + q * 64;
    const float* Wz = Whh + (size_t)(H_DIM + j) * H_DIM + q * 64;
    const float* Wn = Whh + (size_t)(2 * H_DIM + j) * H_DIM + q * 64;
#pragma unroll
    for (int i = 0; i < 32; ++i) {
      whr[i] = packh2(Wr[2 * i], Wr[2 * i + 1]);
      whz[i] = packh2(Wz[2 * i], Wz[2 * i + 1]);
      whn[i] = packh2(Wn[2 * i], Wn[2 * i + 1]);
    }
  }
  const float cbr  = bih[j] + bhh[j];
  const float cbz  = bih[H_DIM + j] + bhh[H_DIM + j];
  const float bin_ = bih[2 * H_DIM + j];
  const float bhn  = bhh[2 * H_DIM + j];

  // ---- Wfc fragments (stationary; 16 regs) ----
  half8 fcfrag[4];
#pragma unroll
  for (int ks = 0; ks < 4; ++ks) {
    half8 v;
#pragma unroll
    for (int e = 0; e < 8; ++e) {
      int cc = ks * 32 + quad * 8 + e;
      v[e] = (col < K_CLS) ? (_Float16)Wfc[(size_t)col * (2 * H_DIM) + dir * H_DIM + cc]
                           : (_Float16)0.f;
    }
    fcfrag[ks] = v;
  }

  if (tid < 128) hbuf[0][tid] = (_Float16)0.f;

  // ---- x prefetch: thread covers row s_row, 16 consecutive floats ----
  const int s_row = tid >> 3;          // 0..31
  const int cbase = (tid & 7) * 16;    // 0..112
  float4 px0, px1, px2, px3;
  {
    int t0 = dir ? (T_LEN - 1 - s_row) : s_row;
    const float* xp = x + ((size_t)b * T_LEN + t0) * DX + cbase;
    px0 = *(const float4*)xp;       px1 = *(const float4*)(xp + 4);
    px2 = *(const float4*)(xp + 8); px3 = *(const float4*)(xp + 12);
  }

  float hold = 0.f;
  __syncthreads();

  for (int c = 0; c < NCHUNKS; ++c) {
    // ---- stage x chunk into LDS (f16) ----
    {
      half8 lo, hi;
      lo[0] = (_Float16)px0.x; lo[1] = (_Float16)px0.y; lo[2] = (_Float16)px0.z; lo[3] = (_Float16)px0.w;
      lo[4] = (_Float16)px1.x; lo[5] = (_Float16)px1.y; lo[6] = (_Float16)px1.z; lo[7] = (_Float16)px1.w;
      hi[0] = (_Float16)px2.x; hi[1] = (_Float16)px2.y; hi[2] = (_Float16)px2.z; hi[3] = (_Float16)px2.w;
      hi[4] = (_Float16)px3.x; hi[5] = (_Float16)px3.y; hi[6] = (_Float16)px3.z; hi[7] = (_Float16)px3.w;
      *(half8*)&xA[s_row][cbase] = lo;
      *(half8*)&xA[s_row][cbase + 8] = hi;
    }
    __syncthreads();

    // ---- xp = x @ Wih^T for this chunk (MFMA); wave handles 6 gate-tiles ----
#pragma unroll
    for (int nt = 0; nt < 6; ++nt) {
      const int g = (wv * 6 + nt) * 16 + col;
      const float* wsrc = Wih + (size_t)g * DX + quad * 8;
      half8 bf[4];
#pragma unroll
      for (int ks = 0; ks < 4; ++ks) {
        const float* s8 = wsrc + ks * 32;
        half8 v;
#pragma unroll
        for (int e = 0; e < 8; ++e) v[e] = (_Float16)s8[e];
        bf[ks] = v;
      }
      floatx4 a0 = (floatx4){0.f, 0.f, 0.f, 0.f};
      floatx4 a1 = (floatx4){0.f, 0.f, 0.f, 0.f};
#pragma unroll
      for (int ks = 0; ks < 4; ++ks) {
        half8 af0 = *(const half8*)&xA[col][ks * 32 + quad * 8];
        half8 af1 = *(const half8*)&xA[16 + col][ks * 32 + quad * 8];
        a0 = __builtin_amdgcn_mfma_f32_16x16x32_f16(af0, bf[ks], a0, 0, 0, 0);
        a1 = __builtin_amdgcn_mfma_f32_16x16x32_f16(af1, bf[ks], a1, 0, 0, 0);
      }
      const int jj = (g & 127) * 4 + (g >> 7);
#pragma unroll
      for (int i = 0; i < 4; ++i) {
        xh2[quad * 4 + i][jj]      = (_Float16)a0[i];
        xh2[16 + quad * 4 + i][jj] = (_Float16)a1[i];
      }
    }

    // prefetch next chunk's x
    if (c + 1 < NCHUNKS) {
      int s = (c + 1) * CHUNK + s_row;
      int t0 = dir ? (T_LEN - 1 - s) : s;
      const float* xp = x + ((size_t)b * T_LEN + t0) * DX + cbase;
      px0 = *(const float4*)xp;       px1 = *(const float4*)(xp + 4);
      px2 = *(const float4*)(xp + 8); px3 = *(const float4*)(xp + 12);
    }
    __syncthreads();

    // ---- sequential scan ----
    int p = 0;
#pragma unroll 2
    for (int s = 0; s < CHUNK; ++s) {
      const uint2 xv = *(const uint2*)&xh2[s][j * 4];   // xr, xz, xn (+pad)
      const uint4* hb = (const uint4*)&hbuf[p][q * 64];
      uint4 h0 = hb[0], h1 = hb[1], h2 = hb[2], h3 = hb[3];
      uint4 h4 = hb[4], h5 = hb[5], h6 = hb[6], h7 = hb[7];
      unsigned int hh[32];
      hh[0]=h0.x;  hh[1]=h0.y;  hh[2]=h0.z;  hh[3]=h0.w;
      hh[4]=h1.x;  hh[5]=h1.y;  hh[6]=h1.z;  hh[7]=h1.w;
      hh[8]=h2.x;  hh[9]=h2.y;  hh[10]=h2.z; hh[11]=h2.w;
      hh[12]=h3.x; hh[13]=h3.y; hh[14]=h3.z; hh[15]=h3.w;
      hh[16]=h4.x; hh[17]=h4.y; hh[18]=h4.z; hh[19]=h4.w;
      hh[20]=h5.x; hh[21]=h5.y; hh[22]=h5.z; hh[23]=h5.w;
      hh[24]=h6.x; hh[25]=h6.y; hh[26]=h6.z; hh[27]=h6.w;
      hh[28]=h7.x; hh[29]=h7.y; hh[30]=h7.z; hh[31]=h7.w;

      float ar0 = 0.f, ar1 = 0.f, az0 = 0.f, az1 = 0.f, an0 = 0.f, an1 = 0.f;
#pragma unroll
      for (int i = 0; i < 16; ++i) {
        ar0 = dot2f(whr[2 * i],     hh[2 * i],     ar0);
        ar1 = dot2f(whr[2 * i + 1], hh[2 * i + 1], ar1);
        az0 = dot2f(whz[2 * i],     hh[2 * i],     az0);
        az1 = dot2f(whz[2 * i + 1], hh[2 * i + 1], az1);
        an0 = dot2f(whn[2 * i],     hh[2 * i],     an0);
        an1 = dot2f(whn[2 * i + 1], hh[2 * i + 1], an1);
      }
      float ar = dpp_xor1_add(ar0 + ar1);
      float az = dpp_xor1_add(az0 + az1);
      float an = dpp_xor1_add(an0 + an1);

      half2v x01 = __builtin_bit_cast(half2v, xv.x);
      half2v x23 = __builtin_bit_cast(half2v, xv.y);
      float rr = sigm((float)x01.x + cbr + ar);
      float zz = sigm((float)x01.y + cbz + az);
      float nn = tanhfast((float)x23.x + bin_ + rr * (an + bhn));
      hold = nn + zz * (hold - nn);

      if (q == 0) {
        _Float16 hf = (_Float16)hold;
        hbuf[p ^ 1][j] = hf;
        hist[s][j] = hf;
      }
      p ^= 1;
      __syncthreads();
    }

    // ---- fused FC for this chunk ----
    if (wv < 2) {
      const int mt = wv;
      floatx4 facc = (floatx4){0.f, 0.f, 0.f, 0.f};
#pragma unroll
      for (int ks = 0; ks < 4; ++ks) {
        half8 af = *(const half8*)&hist[mt * 16 + col][ks * 32 + quad * 8];
        facc = __builtin_amdgcn_mfma_f32_16x16x32_f16(af, fcfrag[ks], facc, 0, 0, 0);
      }
      if (col < K_CLS) {
#pragma unroll
        for (int i = 0; i < 4; ++i) {
          int s = mt * 16 + quad * 4 + i;
          int t = c * CHUNK + s;
          int tt = dir ? (T_LEN - 1 - t) : t;
          atomicAdd(out + ((size_t)b * T_LEN + tt) * K_CLS + col, facc[i]);
        }
      }
    }
  }
}

extern "C" void kernel_launch(void* const* d_in, const int* in_sizes, int n_in,
                              void* d_out, int out_size, void* d_ws, size_t ws_size,
                              hipStream_t stream) {
  (void)in_sizes; (void)n_in; (void)d_ws; (void)ws_size; (void)out_size;
  const float* x     = (const float*)d_in[0];
  const float* Wih_f = (const float*)d_in[1];
  const float* Whh_f = (const float*)d_in[2];
  const float* bih_f = (const float*)d_in[3];
  const float* bhh_f = (const float*)d_in[4];
  const float* Wih_b = (const float*)d_in[5];
  const float* Whh_b = (const float*)d_in[6];
  const float* bih_b = (const float*)d_in[7];
  const float* bhh_b = (const float*)d_in[8];
  const float* Wfc   = (const float*)d_in[9];
  const float* bfc   = (const float*)d_in[10];
  float* out = (float*)d_out;

  const int n_out = B_SZ * T_LEN * K_CLS;
  init_out_kernel<<<(n_out + 255) / 256, 256, 0, stream>>>(out, bfc);
  gru_bidir_kernel<<<B_SZ * 2, 256, 0, stream>>>(x, Wih_f, Whh_f, bih_f, bhh_f,
                                                 Wih_b, Whh_b, bih_b, bhh_b, Wfc, out);
}